// Round 1
// 721.879 us; speedup vs baseline: 1.0735x; 1.0735x over previous
//
#include <hip/hip_runtime.h>
#include <cmath>

#define NTOK 32768   // 32*32*32 tokens
#define CF   64      // channels

// ---------------------------------------------------------------------------
// Patch embed directly into [c][n] layout (== h layout; no transpose needed).
// Block = one (z,y) pair: 32 consecutive tokens x 64 channels, 256 threads.
//  - x lines staged straight into transposed LDS tile xsT[tap][xx]
//  - w staged as wT[tap][c] with +1 padding (row stride 65) -> conflict-free
//  - pos read and t write are lane-consecutive in n -> coalesced
// ---------------------------------------------------------------------------
__global__ void patch_kernel(const float* __restrict__ x,
                             const float* __restrict__ w,
                             const float* __restrict__ bias,
                             const float* __restrict__ pos,
                             float* __restrict__ t) {
    __shared__ float xsT[64 * 32];     // [tap][xx], 8 KB
    __shared__ float wT[64 * 65];      // [tap][c] padded, 16.6 KB
    int tid = threadIdx.x;
    int z = blockIdx.x >> 5, y = blockIdx.x & 31;

    for (int k = tid; k < 4096; k += 256) {        // w is [c][tap] row-major
        int c = k >> 6, tap = k & 63;
        wT[tap * 65 + c] = w[k];                   // stride-65 writes: conflict-free
    }
    #pragma unroll
    for (int p = 0; p < 2; ++p) {                  // 512 float4 = 16 x-lines
        int q = tid + p * 256;                     // 0..511
        int r = q >> 5;                            // 0..15 = dz*4+dy
        int col4 = q & 31;                         // token xx
        int dz = r >> 2, dy = r & 3;
        const float4* src = (const float4*)(x + (size_t)((z * 4 + dz) * 128 + (y * 4 + dy)) * 128);
        float4 v = src[col4];                      // fully coalesced
        int tb = dz * 16 + dy * 4;                 // tap = dz*16+dy*4+dx
        xsT[(tb + 0) * 32 + col4] = v.x;
        xsT[(tb + 1) * 32 + col4] = v.y;
        xsT[(tb + 2) * 32 + col4] = v.z;
        xsT[(tb + 3) * 32 + col4] = v.w;
    }
    __syncthreads();

    int xx = tid & 31;                             // token within row
    int ch = tid >> 5;                             // 0..7
    int n = z * 1024 + y * 32 + xx;
    #pragma unroll
    for (int p = 0; p < 8; ++p) {
        int c = ch + p * 8;
        float acc = bias[c];
        #pragma unroll
        for (int k = 0; k < 64; ++k)               // xsT: 32 consec + broadcast; wT: broadcast
            acc += xsT[k * 32 + xx] * wT[k * 65 + c];
        t[c * NTOK + n] = acc + pos[c * NTOK + n]; // both coalesced in n
    }
}

// ---------------------------------------------------------------------------
// Gather + QKV: one selected token per block, 192 threads.
// qkv weights staged in LDS with +1-padded rows: read stride 65 -> no bank
// conflicts (old version: per-lane global row reads = 64-transaction storms).
// ---------------------------------------------------------------------------
__global__ void qkv_kernel(const float* __restrict__ t,
                           const float* __restrict__ w,
                           const float* __restrict__ bias,
                           const int* __restrict__ idx,
                           float* __restrict__ qkv) {
    __shared__ float tv[64];
    __shared__ float ws[192 * 65];    // 49.9 KB, [j][c] padded
    int i = blockIdx.x, j = threadIdx.x;
    int n = idx[i];
    if (j < 64) tv[j] = t[j * NTOK + n];           // 64 scattered 4B loads (tiny)
    for (int k = j; k < 12288; k += 192)           // coalesced global, skewed LDS
        ws[(k >> 6) * 65 + (k & 63)] = w[k];
    __syncthreads();
    float acc = bias[j];
    const float* wr = ws + j * 65;
    #pragma unroll
    for (int c = 0; c < 64; ++c) acc += tv[c] * wr[c];   // tv broadcast, wr stride-65
    qkv[i * 192 + j] = acc;
}

// ---------------------------------------------------------------------------
// Attention + proj + residual + scatter fused: one wave per query row.
// Scores via float4 K-row reads; softmax shuffle-reduced; PV coalesced.
// proj_w staged transposed+padded in LDS: pwt[q][c] = pw[c][q], stride 65.
// ---------------------------------------------------------------------------
__global__ void attn_proj_kernel(const float* __restrict__ qkv,
                                 float* __restrict__ t,
                                 const float* __restrict__ pw,
                                 const float* __restrict__ pb,
                                 const int* __restrict__ idx,
                                 int M) {
    __shared__ float qs[64];
    __shared__ float yv[64];
    __shared__ float p[512];          // M <= 280
    __shared__ float pwt[64 * 65];    // 16.6 KB
    int i = blockIdx.x, lane = threadIdx.x;       // 64 threads = 1 wave
    qs[lane] = qkv[i * 192 + lane];
    for (int k = lane; k < 4096; k += 64)          // coalesced read, skewed write
        pwt[(k & 63) * 65 + (k >> 6)] = pw[k];     // pwt[q][c] = pw[c][q]
    __syncthreads();

    const float scale = 0.125f;                    // 1/sqrt(64)
    for (int j = lane; j < M; j += 64) {
        const float4* kr = (const float4*)(qkv + j * 192 + 64);
        float acc = 0.f;
        #pragma unroll
        for (int c4 = 0; c4 < 16; ++c4) {
            float4 kv = kr[c4];
            acc += qs[c4 * 4 + 0] * kv.x + qs[c4 * 4 + 1] * kv.y
                 + qs[c4 * 4 + 2] * kv.z + qs[c4 * 4 + 3] * kv.w;
        }
        p[j] = acc * scale;
    }
    __syncthreads();
    float m = -INFINITY;
    for (int j = lane; j < M; j += 64) m = fmaxf(m, p[j]);
    #pragma unroll
    for (int off = 32; off > 0; off >>= 1) m = fmaxf(m, __shfl_xor(m, off));
    float s = 0.f;
    for (int j = lane; j < M; j += 64) { float e = expf(p[j] - m); p[j] = e; s += e; }
    #pragma unroll
    for (int off = 32; off > 0; off >>= 1) s += __shfl_xor(s, off);
    __syncthreads();
    float inv = 1.f / s;
    float acc = 0.f;
    for (int j = 0; j < M; ++j)                    // p broadcast, V coalesced
        acc += p[j] * qkv[j * 192 + 128 + lane];
    float yc = acc * inv;                          // y[i][lane]
    yv[lane] = yc;
    __syncthreads();
    float facc = pb[lane] + yc;                    // + residual
    #pragma unroll
    for (int q = 0; q < 64; ++q)                   // yv broadcast, pwt stride-65
        facc += yv[q] * pwt[q * 65 + lane];
    t[lane * NTOK + idx[i]] = facc;                // scatter into [c][n]
}

// ---------------------------------------------------------------------------
// Trilinear x4 upsample (unchanged; reads t which is already [c][z][y][x]).
// ---------------------------------------------------------------------------
__global__ void upsample_kernel(const float* __restrict__ h, float* __restrict__ out) {
    int bc = blockIdx.x;
    int c = bc >> 7, zo = bc & 127;
    __shared__ float pz[1024];        // z-lerped plane, 32x32
    __shared__ float wtab[128];
    __shared__ int   itab[128];
    int tid = threadIdx.x;            // 256
    const float scale = (float)(31.0 / 127.0);
    if (tid < 128) {
        float p = (float)tid * scale;
        int i0 = (int)floorf(p);
        if (i0 > 31) i0 = 31;
        itab[tid] = i0;
        wtab[tid] = p - (float)i0;
    }
    float pzf = (float)zo * scale;
    int zi0 = (int)floorf(pzf);
    if (zi0 > 31) zi0 = 31;
    int zi1 = min(zi0 + 1, 31);
    float wz = pzf - (float)zi0;
    const float4* pl0 = (const float4*)(h + (c * 32 + zi0) * 1024);
    const float4* pl1 = (const float4*)(h + (c * 32 + zi1) * 1024);
    float4 a = pl0[tid];
    float4 b = pl1[tid];
    float4 r;
    r.x = a.x * (1.f - wz) + b.x * wz;
    r.y = a.y * (1.f - wz) + b.y * wz;
    r.z = a.z * (1.f - wz) + b.z * wz;
    r.w = a.w * (1.f - wz) + b.w * wz;
    ((float4*)pz)[tid] = r;
    __syncthreads();
    float4* o = (float4*)(out + (size_t)(c * 128 + zo) * 16384);
    for (int q = 0; q < 16; ++q) {
        int Q = q * 256 + tid;
        int yo = Q >> 5, xq = Q & 31;
        int yi0 = itab[yo];
        float wy = wtab[yo];
        int yi1 = min(yi0 + 1, 31);
        const float* r0 = pz + yi0 * 32;
        const float* r1 = pz + yi1 * 32;
        float vv[4];
        #pragma unroll
        for (int k = 0; k < 4; ++k) {
            int xo = xq * 4 + k;
            int xi0 = itab[xo];
            float wx = wtab[xo];
            int xi1 = min(xi0 + 1, 31);
            float v0 = r0[xi0] * (1.f - wx) + r0[xi1] * wx;
            float v1 = r1[xi0] * (1.f - wx) + r1[xi1] * wx;
            vv[k] = v0 * (1.f - wy) + v1 * wy;
        }
        float4 v; v.x = vv[0]; v.y = vv[1]; v.z = vv[2]; v.w = vv[3];
        o[Q] = v;
    }
}

// ---------------------------------------------------------------------------
extern "C" void kernel_launch(void* const* d_in, const int* in_sizes, int n_in,
                              void* d_out, int out_size, void* d_ws, size_t ws_size,
                              hipStream_t stream) {
    const float* x       = (const float*)d_in[0];
    const float* w_patch = (const float*)d_in[1];
    const float* b_patch = (const float*)d_in[2];
    const float* pos     = (const float*)d_in[3];
    const float* qkv_w[3]  = {(const float*)d_in[4],  (const float*)d_in[8],  (const float*)d_in[12]};
    const float* qkv_b[3]  = {(const float*)d_in[5],  (const float*)d_in[9],  (const float*)d_in[13]};
    const float* proj_w[3] = {(const float*)d_in[6],  (const float*)d_in[10], (const float*)d_in[14]};
    const float* proj_b[3] = {(const float*)d_in[7],  (const float*)d_in[11], (const float*)d_in[15]};
    float* out = (float*)d_out;

    // ws layout: t ([c][n] == h layout) [0,8MB) ; qkv [8MB,8MB+768KB) ; idx at 9MB.
    char* ws = (char*)d_ws;
    if (ws_size < (size_t)(16u << 20)) return;
    float* t   = (float*)ws;
    float* qkv = (float*)(ws + (8u << 20));
    int*   idx = (int*)  (ws + (9u << 20));

    // Host-side index lists (deterministic, same math as reference selection:
    // d = sqrt(dd) is integral iff dd is a perfect square; selected iff s%dil==0,
    // which covers d==0). Static storage so the graph's memcpy node can re-read it.
    static int h_idx[3 * 1024];
    int M[3];
    for (int di = 0; di < 3; ++di) {
        int dil = 2 * (di + 1), cnt = 0;
        for (int n = 0; n < NTOK; ++n) {
            int z = n >> 10, yy = (n >> 5) & 31, xx = n & 31;
            int a = z - 16, b = yy - 16, c = xx - 16;
            int dd = a * a + b * b + c * c;
            int s = (int)(std::sqrt((double)dd) + 0.5);
            if (s * s == dd && (s % dil) == 0) h_idx[di * 1024 + cnt++] = n;
        }
        M[di] = cnt;   // expected 280 / 64 / 139
    }
    hipMemcpyAsync(idx, h_idx, sizeof(h_idx), hipMemcpyHostToDevice, stream);

    patch_kernel<<<1024, 256, 0, stream>>>(x, w_patch, b_patch, pos, t);
    for (int di = 0; di < 3; ++di) {
        qkv_kernel<<<M[di], 192, 0, stream>>>(t, qkv_w[di], qkv_b[di], idx + di * 1024, qkv);
        attn_proj_kernel<<<M[di], 64, 0, stream>>>(qkv, t, proj_w[di], proj_b[di], idx + di * 1024, M[di]);
    }
    upsample_kernel<<<CF * 128, 256, 0, stream>>>(t, out);
}

// Round 2
// 721.587 us; speedup vs baseline: 1.0739x; 1.0004x over previous
//
#include <hip/hip_runtime.h>
#include <cmath>

#define NTOK 32768   // 32*32*32 tokens
#define CF   64      // channels
#define TSP  66      // LDS token-row pitch (floats): 8B-aligned, 2-way bank alias (free)

// ---------------------------------------------------------------------------
// prep: fold the dst-block algebra into two 64x64 matrices per dilation.
//   scores: s_j = (A t_i + bq') . t_j + w2 . t_i + c0,  A  = scale * W_k^T W_q
//   output: out_i = B u + bb, u = sum_j softmax_j t_j,  B  = (W_p + I) W_v
// Stored TRANSPOSED (At[k][c] = A[c][k]) so the matvec reads are coalesced.
// One block per dilation, 256 threads.
// ---------------------------------------------------------------------------
__global__ void prep_kernel(const float* __restrict__ qw0, const float* __restrict__ qb0,
                            const float* __restrict__ pw0, const float* __restrict__ pb0,
                            const float* __restrict__ qw1, const float* __restrict__ qb1,
                            const float* __restrict__ pw1, const float* __restrict__ pb1,
                            const float* __restrict__ qw2, const float* __restrict__ qb2,
                            const float* __restrict__ pw2, const float* __restrict__ pb2,
                            float* __restrict__ consts) {
    int di = blockIdx.x;
    const float* qw = di == 0 ? qw0 : (di == 1 ? qw1 : qw2);   // [192][64]
    const float* qb = di == 0 ? qb0 : (di == 1 ? qb1 : qb2);   // [192]
    const float* pw = di == 0 ? pw0 : (di == 1 ? pw1 : pw2);   // [64][64]
    const float* pb = di == 0 ? pb0 : (di == 1 ? pb1 : pb2);   // [64]
    float* base = consts + di * 8448;
    float* At  = base;          // [k][c] = scale * sum_m W_k[m][c] W_q[m][k]
    float* Bt  = base + 4096;   // [k][c] = sum_m (W_p+I)[c][m] W_v[m][k]
    float* bqp = base + 8192;
    float* w2  = base + 8256;
    float* bb  = base + 8320;
    float* c0  = base + 8384;
    int tid = threadIdx.x;
    const float scale = 0.125f;
    // At: lanes consecutive in c -> W_k reads coalesced, W_q broadcast.
    for (int o = tid; o < 4096; o += 256) {
        int k = o >> 6, c = o & 63;
        float a = 0.f;
        for (int m = 0; m < 64; ++m)
            a += qw[(64 + m) * 64 + c] * qw[m * 64 + k];
        At[k * 64 + c] = scale * a;
    }
    // Bt: lanes consecutive in k -> W_v reads coalesced, pw broadcast.
    for (int o = tid; o < 4096; o += 256) {
        int c = o >> 6, k = o & 63;
        float b = 0.f;
        for (int m = 0; m < 64; ++m) {
            float pp = pw[c * 64 + m] + (c == m ? 1.f : 0.f);
            b += pp * qw[(128 + m) * 64 + k];
        }
        Bt[k * 64 + c] = b;     // scattered write, 16KB total: negligible
    }
    if (tid < 64) {
        int c = tid;
        float a = 0.f, w = 0.f, b = 0.f;
        for (int m = 0; m < 64; ++m) {
            a += qw[(64 + m) * 64 + c] * qb[m];        // W_k^T b_q
            w += qb[64 + m] * qw[m * 64 + c];          // W_q^T b_k
            float pp = pw[c * 64 + m] + (c == m ? 1.f : 0.f);
            b += pp * qb[128 + m];                     // (W_p+I) b_v
        }
        bqp[c] = scale * a;
        w2[c]  = scale * w;
        bb[c]  = b + pb[c];
        if (c == 0) {
            float s = 0.f;
            for (int m = 0; m < 64; ++m) s += qb[m] * qb[64 + m];
            c0[0] = scale * s;
        }
    }
}

// ---------------------------------------------------------------------------
// Patch embed -> BOTH layouts: tnc[n][c] (fused-dst gathers) and tcn[c][n]
// (upsample). Results staged in res[64][33] so both global writes coalesce.
// ---------------------------------------------------------------------------
__global__ __launch_bounds__(256) void patch_kernel(const float* __restrict__ x,
                             const float* __restrict__ w,
                             const float* __restrict__ bias,
                             const float* __restrict__ pos,
                             float* __restrict__ tnc,
                             float* __restrict__ tcn) {
    __shared__ float xsT[64 * 32];     // [tap][xx]
    __shared__ float wT[64 * 65];      // [tap][c] padded
    __shared__ float res[64 * 33];     // [c][xx] padded
    int tid = threadIdx.x;
    int z = blockIdx.x >> 5, y = blockIdx.x & 31;

    for (int k = tid; k < 4096; k += 256) {
        int c = k >> 6, tap = k & 63;
        wT[tap * 65 + c] = w[k];
    }
    #pragma unroll
    for (int p = 0; p < 2; ++p) {
        int q = tid + p * 256;
        int r = q >> 5;
        int col4 = q & 31;
        int dz = r >> 2, dy = r & 3;
        const float4* src = (const float4*)(x + (size_t)((z * 4 + dz) * 128 + (y * 4 + dy)) * 128);
        float4 v = src[col4];
        int tb = dz * 16 + dy * 4;
        xsT[(tb + 0) * 32 + col4] = v.x;
        xsT[(tb + 1) * 32 + col4] = v.y;
        xsT[(tb + 2) * 32 + col4] = v.z;
        xsT[(tb + 3) * 32 + col4] = v.w;
    }
    __syncthreads();

    int xx = tid & 31;
    int ch = tid >> 5;
    int nb = z * 1024 + y * 32;
    #pragma unroll
    for (int p = 0; p < 8; ++p) {
        int c = ch + p * 8;
        float acc = bias[c];
        #pragma unroll
        for (int k = 0; k < 64; ++k)
            acc += xsT[k * 32 + xx] * wT[k * 65 + c];
        res[c * 33 + xx] = acc + pos[c * NTOK + nb + xx];
    }
    __syncthreads();
    for (int q = tid; q < 2048; q += 256) {        // tnc: coalesced in c
        int tok = q >> 6, c = q & 63;
        tnc[(size_t)(nb + tok) * 64 + c] = res[c * 33 + tok];
    }
    for (int q = tid; q < 2048; q += 256) {        // tcn: coalesced in n
        int c = q >> 5, x2 = q & 31;
        tcn[(size_t)c * NTOK + nb + x2] = res[c * 33 + x2];
    }
}

// ---------------------------------------------------------------------------
// Fused dst block (per dilation): gather M tokens -> LDS once per block,
// then per query (4/block, one wave each):
//   kq = A t_i + bq'   (coalesced At reads, LDS-broadcast t_i)
//   s_j = kq . t_j + (w2.t_i + c0) ; softmax in registers (p[5])
//   u = sum_j p_j t_j ; out = B u + bb  -> yout (scattered later, race-free)
// ---------------------------------------------------------------------------
__global__ __launch_bounds__(256) void dst_kernel(const float* __restrict__ tnc,
                           const float* __restrict__ cbase,
                           const int* __restrict__ idx,
                           float* __restrict__ yout, int M) {
    __shared__ float ts[280 * TSP];   // 73.9 KB: all M token rows
    __shared__ float kqs[4 * 64];     // per-wave kq vector (reused for u)
    const float* At  = cbase;
    const float* Bt  = cbase + 4096;
    const float* bqp = cbase + 8192;
    const float* w2v = cbase + 8256;
    const float* bbv = cbase + 8320;
    const float* c0v = cbase + 8384;
    int tid = threadIdx.x;
    for (int q = tid; q < M * 16; q += 256) {      // float4 gather, coalesced rows
        int j = q >> 4, c4 = (q & 15) << 2;
        const float4 v = *(const float4*)(tnc + (size_t)idx[j] * 64 + c4);
        float* d = ts + j * TSP + c4;
        d[0] = v.x; d[1] = v.y; d[2] = v.z; d[3] = v.w;
    }
    __syncthreads();                                // only barrier in kernel
    int w = tid >> 6, lane = tid & 63;
    int qi = blockIdx.x * 4 + w;
    if (qi >= M) return;
    const float* trow = ts + qi * TSP;
    float kq = bqp[lane];
    #pragma unroll 16
    for (int k = 0; k < 64; ++k)
        kq += At[k * 64 + lane] * trow[k];          // coalesced / broadcast
    kqs[w * 64 + lane] = kq;                        // intra-wave: no barrier needed
    float sb = w2v[lane] * trow[lane];
    #pragma unroll
    for (int off = 32; off > 0; off >>= 1) sb += __shfl_xor(sb, off);
    sb += c0v[0];

    float p[5];
    float mx = -INFINITY;
    const float2* kq2 = (const float2*)(kqs + w * 64);
    #pragma unroll
    for (int it = 0; it < 5; ++it) {
        int j = it * 64 + lane;
        p[it] = -INFINITY;
        if (j < M) {
            const float2* tr2 = (const float2*)(ts + j * TSP);
            float s = sb;
            #pragma unroll 8
            for (int c = 0; c < 32; ++c) {
                float2 a = kq2[c]; float2 b = tr2[c];
                s += a.x * b.x + a.y * b.y;
            }
            p[it] = s; mx = fmaxf(mx, s);
        }
    }
    #pragma unroll
    for (int off = 32; off > 0; off >>= 1) mx = fmaxf(mx, __shfl_xor(mx, off));
    float ssum = 0.f;
    #pragma unroll
    for (int it = 0; it < 5; ++it) {
        int j = it * 64 + lane;
        float e = (j < M) ? expf(p[it] - mx) : 0.f;
        p[it] = e; ssum += e;
    }
    #pragma unroll
    for (int off = 32; off > 0; off >>= 1) ssum += __shfl_xor(ssum, off);
    float inv = 1.f / ssum;

    float u = 0.f;
    #pragma unroll
    for (int it = 0; it < 5; ++it) {               // static p[it] (no scratch)
        int jb = it * 64;
        if (jb < M) {
            int cnt = min(64, M - jb);
            for (int jj = 0; jj < cnt; ++jj) {
                float pj = __shfl(p[it], jj);      // broadcast p_j
                u += pj * ts[(jb + jj) * TSP + lane];   // conflict-free row read
            }
        }
    }
    u *= inv;
    kqs[w * 64 + lane] = u;                         // reuse slot (intra-wave)
    float o = bbv[lane];
    const float2* u2 = (const float2*)(kqs + w * 64);
    #pragma unroll 8
    for (int k = 0; k < 32; ++k) {
        float2 uu = u2[k];
        o += Bt[(2 * k) * 64 + lane] * uu.x + Bt[(2 * k + 1) * 64 + lane] * uu.y;
    }
    yout[qi * 64 + lane] = o;
}

// ---------------------------------------------------------------------------
// Race-free scatter of the dilation's outputs into both t layouts.
// ---------------------------------------------------------------------------
__global__ void scatter_kernel(const float* __restrict__ yout,
                               float* __restrict__ tnc,
                               float* __restrict__ tcn,
                               const int* __restrict__ idx) {
    int i = blockIdx.x, c = threadIdx.x;           // 64 threads
    int n = idx[i];
    float v = yout[i * 64 + c];
    tnc[(size_t)n * 64 + c] = v;
    tcn[(size_t)c * NTOK + n] = v;
}

// ---------------------------------------------------------------------------
// Trilinear x4 upsample (unchanged; reads tcn = [c][z][y][x]).
// ---------------------------------------------------------------------------
__global__ void upsample_kernel(const float* __restrict__ h, float* __restrict__ out) {
    int bc = blockIdx.x;
    int c = bc >> 7, zo = bc & 127;
    __shared__ float pz[1024];
    __shared__ float wtab[128];
    __shared__ int   itab[128];
    int tid = threadIdx.x;
    const float scale = (float)(31.0 / 127.0);
    if (tid < 128) {
        float p = (float)tid * scale;
        int i0 = (int)floorf(p);
        if (i0 > 31) i0 = 31;
        itab[tid] = i0;
        wtab[tid] = p - (float)i0;
    }
    float pzf = (float)zo * scale;
    int zi0 = (int)floorf(pzf);
    if (zi0 > 31) zi0 = 31;
    int zi1 = min(zi0 + 1, 31);
    float wz = pzf - (float)zi0;
    const float4* pl0 = (const float4*)(h + (c * 32 + zi0) * 1024);
    const float4* pl1 = (const float4*)(h + (c * 32 + zi1) * 1024);
    float4 a = pl0[tid];
    float4 b = pl1[tid];
    float4 r;
    r.x = a.x * (1.f - wz) + b.x * wz;
    r.y = a.y * (1.f - wz) + b.y * wz;
    r.z = a.z * (1.f - wz) + b.z * wz;
    r.w = a.w * (1.f - wz) + b.w * wz;
    ((float4*)pz)[tid] = r;
    __syncthreads();
    float4* o = (float4*)(out + (size_t)(c * 128 + zo) * 16384);
    for (int q = 0; q < 16; ++q) {
        int Q = q * 256 + tid;
        int yo = Q >> 5, xq = Q & 31;
        int yi0 = itab[yo];
        float wy = wtab[yo];
        int yi1 = min(yi0 + 1, 31);
        const float* r0 = pz + yi0 * 32;
        const float* r1 = pz + yi1 * 32;
        float vv[4];
        #pragma unroll
        for (int k = 0; k < 4; ++k) {
            int xo = xq * 4 + k;
            int xi0 = itab[xo];
            float wx = wtab[xo];
            int xi1 = min(xi0 + 1, 31);
            float v0 = r0[xi0] * (1.f - wx) + r0[xi1] * wx;
            float v1 = r1[xi0] * (1.f - wx) + r1[xi1] * wx;
            vv[k] = v0 * (1.f - wy) + v1 * wy;
        }
        float4 v; v.x = vv[0]; v.y = vv[1]; v.z = vv[2]; v.w = vv[3];
        o[Q] = v;
    }
}

// ---------------------------------------------------------------------------
extern "C" void kernel_launch(void* const* d_in, const int* in_sizes, int n_in,
                              void* d_out, int out_size, void* d_ws, size_t ws_size,
                              hipStream_t stream) {
    const float* x       = (const float*)d_in[0];
    const float* w_patch = (const float*)d_in[1];
    const float* b_patch = (const float*)d_in[2];
    const float* pos     = (const float*)d_in[3];
    float* out = (float*)d_out;

    // ws layout: tcn [0,8MB) ; tnc [8,16MB) ; yout @16MB ; idx @17MB ; consts @18MB
    char* ws = (char*)d_ws;
    if (ws_size < (size_t)(20u << 20)) return;
    float* tcn    = (float*)ws;
    float* tnc    = (float*)(ws + (8u << 20));
    float* yout   = (float*)(ws + (16u << 20));
    int*   idx    = (int*)  (ws + (17u << 20));
    float* consts = (float*)(ws + (18u << 20));

    // Host-side index lists (deterministic; same math as reference selection).
    static int h_idx[3 * 1024];
    int M[3];
    for (int di = 0; di < 3; ++di) {
        int dil = 2 * (di + 1), cnt = 0;
        for (int n = 0; n < NTOK; ++n) {
            int z = n >> 10, yy = (n >> 5) & 31, xx = n & 31;
            int a = z - 16, b = yy - 16, c = xx - 16;
            int dd = a * a + b * b + c * c;
            int s = (int)(std::sqrt((double)dd) + 0.5);
            if (s * s == dd && (s % dil) == 0) h_idx[di * 1024 + cnt++] = n;
        }
        M[di] = cnt;   // expected 280 / 64 / 139
    }
    hipMemcpyAsync(idx, h_idx, sizeof(h_idx), hipMemcpyHostToDevice, stream);

    prep_kernel<<<3, 256, 0, stream>>>(
        (const float*)d_in[4],  (const float*)d_in[5],  (const float*)d_in[6],  (const float*)d_in[7],
        (const float*)d_in[8],  (const float*)d_in[9],  (const float*)d_in[10], (const float*)d_in[11],
        (const float*)d_in[12], (const float*)d_in[13], (const float*)d_in[14], (const float*)d_in[15],
        consts);
    patch_kernel<<<1024, 256, 0, stream>>>(x, w_patch, b_patch, pos, tnc, tcn);
    for (int di = 0; di < 3; ++di) {
        dst_kernel<<<(M[di] + 3) / 4, 256, 0, stream>>>(tnc, consts + di * 8448, idx + di * 1024, yout, M[di]);
        scatter_kernel<<<M[di], 64, 0, stream>>>(yout, tnc, tcn, idx + di * 1024);
    }
    upsample_kernel<<<CF * 128, 256, 0, stream>>>(tcn, out);
}

// Round 3
// 650.447 us; speedup vs baseline: 1.1914x; 1.1094x over previous
//
#include <hip/hip_runtime.h>
#include <cmath>

#define NTOK 32768   // 32*32*32 tokens
#define CF   64      // channels
#define TSP  66      // LDS token-row pitch (floats): 8B-aligned, 2-way bank alias (free)

typedef __attribute__((ext_vector_type(4))) float f32x4;

// Host->device blob layout (ints)
#define OFF_IDX2 0      // 280 token ids (dil=2 set, ascending)
#define OFF_T4   512    // 64 token ids (dil=4)
#define OFF_T6   768    // 139 token ids (dil=6)
#define OFF_G1   1024   // 64 gather rows for round 1 (into yout)
#define OFF_G2   1280   // 139 gather rows for round 2 (into yout)
#define OFF_W0   1536   // 280 flags: round-0 result is final -> write tcn
#define OFF_W1   2048   // 64 flags: round-1 result is final -> write tcn
#define BLOB_INTS 2112

// ---------------------------------------------------------------------------
// Fused patch embed + prep.
// Blocks [0,1024): patch embed -> tnc[n][c] (dst gathers) and tcn[c][n] (upsample).
// Blocks [1024,1121): prep — fold dst algebra into per-dilation constants:
//   scores: s_j = (A t_i + bq') . t_j + w2 . t_i + c0,  A = scale * W_k^T W_q
//   output: out_i = B u + bb, u = sum_j softmax_j t_j,  B = (W_p + I) W_v
// consts stored transposed (At[k][c]) so dst matvec reads coalesce.
// ---------------------------------------------------------------------------
__global__ __launch_bounds__(256) void patch_prep_kernel(
    const float* __restrict__ x, const float* __restrict__ w,
    const float* __restrict__ bias, const float* __restrict__ pos,
    float* __restrict__ tnc, float* __restrict__ tcn,
    const float* __restrict__ qw0, const float* __restrict__ qb0,
    const float* __restrict__ pw0, const float* __restrict__ pb0,
    const float* __restrict__ qw1, const float* __restrict__ qb1,
    const float* __restrict__ pw1, const float* __restrict__ pb1,
    const float* __restrict__ qw2, const float* __restrict__ qb2,
    const float* __restrict__ pw2, const float* __restrict__ pb2,
    float* __restrict__ consts) {
    __shared__ float xsT[64 * 32];     // [tap][xx]
    __shared__ float wT[64 * 65];      // [tap][c] padded
    __shared__ float res[64 * 33];     // [c][xx] padded
    int tid = threadIdx.x;

    if (blockIdx.x >= 1024) {          // ---- prep branch (distributed) ----
        int gid = (blockIdx.x - 1024) * 256 + tid;
        if (gid >= 3 * 8257) return;
        int di = gid / 8257, o = gid % 8257;
        const float* qw = di == 0 ? qw0 : (di == 1 ? qw1 : qw2);   // [192][64]
        const float* qb = di == 0 ? qb0 : (di == 1 ? qb1 : qb2);   // [192]
        const float* pw = di == 0 ? pw0 : (di == 1 ? pw1 : pw2);   // [64][64]
        const float* pb = di == 0 ? pb0 : (di == 1 ? pb1 : pb2);   // [64]
        float* base = consts + di * 8448;
        const float scale = 0.125f;
        if (o < 4096) {                // At[k][c]: lanes consecutive in c -> coalesced
            int k = o >> 6, c = o & 63;
            float a = 0.f;
            for (int m = 0; m < 64; ++m)
                a += qw[(64 + m) * 64 + c] * qw[m * 64 + k];
            base[o] = scale * a;
        } else if (o < 8192) {         // Bt[k][c]: lanes consecutive in k -> coalesced
            int oo = o - 4096;
            int c = oo >> 6, k = oo & 63;
            float b = 0.f;
            for (int m = 0; m < 64; ++m) {
                float pp = pw[c * 64 + m] + (c == m ? 1.f : 0.f);
                b += pp * qw[(128 + m) * 64 + k];
            }
            base[4096 + k * 64 + c] = b;
        } else if (o < 8256) {         // per-c vectors
            int c = o - 8192;
            float a = 0.f, wv = 0.f, b = 0.f;
            for (int m = 0; m < 64; ++m) {
                a += qw[(64 + m) * 64 + c] * qb[m];        // W_k^T b_q
                wv += qb[64 + m] * qw[m * 64 + c];         // W_q^T b_k
                float pp = pw[c * 64 + m] + (c == m ? 1.f : 0.f);
                b += pp * qb[128 + m];                     // (W_p+I) b_v
            }
            base[8192 + c] = scale * a;
            base[8256 + c] = scale * wv;
            base[8320 + c] = b + pb[c];
        } else {                       // c0
            float s = 0.f;
            for (int m = 0; m < 64; ++m) s += qb[m] * qb[64 + m];
            base[8384] = scale * s;
        }
        return;
    }

    // ---- patch branch ----
    int z = blockIdx.x >> 5, y = blockIdx.x & 31;
    for (int k = tid; k < 4096; k += 256) {
        int c = k >> 6, tap = k & 63;
        wT[tap * 65 + c] = w[k];
    }
    #pragma unroll
    for (int p = 0; p < 2; ++p) {
        int q = tid + p * 256;
        int r = q >> 5;
        int col4 = q & 31;
        int dz = r >> 2, dy = r & 3;
        const float4* src = (const float4*)(x + (size_t)((z * 4 + dz) * 128 + (y * 4 + dy)) * 128);
        float4 v = src[col4];
        int tb = dz * 16 + dy * 4;
        xsT[(tb + 0) * 32 + col4] = v.x;
        xsT[(tb + 1) * 32 + col4] = v.y;
        xsT[(tb + 2) * 32 + col4] = v.z;
        xsT[(tb + 3) * 32 + col4] = v.w;
    }
    __syncthreads();

    int xx = tid & 31;
    int ch = tid >> 5;
    int nb = z * 1024 + y * 32;
    #pragma unroll
    for (int p = 0; p < 8; ++p) {
        int c = ch + p * 8;
        float acc = bias[c];
        #pragma unroll
        for (int k = 0; k < 64; ++k)
            acc += xsT[k * 32 + xx] * wT[k * 65 + c];
        res[c * 33 + xx] = acc + pos[c * NTOK + nb + xx];
    }
    __syncthreads();
    for (int q = tid; q < 2048; q += 256) {        // tnc: coalesced in c
        int tok = q >> 6, c = q & 63;
        tnc[(size_t)(nb + tok) * 64 + c] = res[c * 33 + tok];
    }
    for (int q = tid; q < 2048; q += 256) {        // tcn: coalesced in n
        int c = q >> 5, x2 = q & 31;
        tcn[(size_t)c * NTOK + nb + x2] = res[c * 33 + x2];
    }
}

// ---------------------------------------------------------------------------
// Fused dst round. Gathers M rows from gp[gidx[j]] (64-float rows), computes
// all M queries (4/block, one wave each), writes per-query output to ydst row
// qi (if non-null) and/or directly to tcn when this round's value is final.
// No scatter kernels, no cross-round patching: value routing is precomputed.
// ---------------------------------------------------------------------------
__global__ __launch_bounds__(256) void dst_kernel(
    const float* __restrict__ gp, const int* __restrict__ gidx,
    const float* __restrict__ cbase, float* __restrict__ ydst,
    const int* __restrict__ tok, const int* __restrict__ wflag,
    float* __restrict__ tcn, int M) {
    __shared__ float ts[280 * TSP];   // 73.9 KB
    __shared__ float kqs[4 * 64];
    const float* At  = cbase;
    const float* Bt  = cbase + 4096;
    const float* bqp = cbase + 8192;
    const float* w2v = cbase + 8256;
    const float* bbv = cbase + 8320;
    const float* c0v = cbase + 8384;
    int tid = threadIdx.x;
    for (int q = tid; q < M * 16; q += 256) {      // row gather, coalesced
        int j = q >> 4, c4 = (q & 15) << 2;
        const float4 v = *(const float4*)(gp + (size_t)gidx[j] * 64 + c4);
        float* d = ts + j * TSP + c4;
        d[0] = v.x; d[1] = v.y; d[2] = v.z; d[3] = v.w;
    }
    __syncthreads();                                // only barrier
    int w = tid >> 6, lane = tid & 63;
    int qi = blockIdx.x * 4 + w;
    if (qi >= M) return;
    const float* trow = ts + qi * TSP;
    float kq = bqp[lane];
    #pragma unroll 16
    for (int k = 0; k < 64; ++k)
        kq += At[k * 64 + lane] * trow[k];          // coalesced / broadcast
    kqs[w * 64 + lane] = kq;                        // intra-wave
    float sb = w2v[lane] * trow[lane];
    #pragma unroll
    for (int off = 32; off > 0; off >>= 1) sb += __shfl_xor(sb, off);
    sb += c0v[0];

    float p[5];
    float mx = -INFINITY;
    const float2* kq2 = (const float2*)(kqs + w * 64);
    #pragma unroll
    for (int it = 0; it < 5; ++it) {
        int j = it * 64 + lane;
        p[it] = -INFINITY;
        if (j < M) {
            const float2* tr2 = (const float2*)(ts + j * TSP);
            float s = sb;
            #pragma unroll 8
            for (int c = 0; c < 32; ++c) {
                float2 a = kq2[c]; float2 b = tr2[c];
                s += a.x * b.x + a.y * b.y;
            }
            p[it] = s; mx = fmaxf(mx, s);
        }
    }
    #pragma unroll
    for (int off = 32; off > 0; off >>= 1) mx = fmaxf(mx, __shfl_xor(mx, off));
    float ssum = 0.f;
    #pragma unroll
    for (int it = 0; it < 5; ++it) {
        int j = it * 64 + lane;
        float e = (j < M) ? expf(p[it] - mx) : 0.f;
        p[it] = e; ssum += e;
    }
    #pragma unroll
    for (int off = 32; off > 0; off >>= 1) ssum += __shfl_xor(ssum, off);
    float inv = 1.f / ssum;

    float u = 0.f;
    #pragma unroll
    for (int it = 0; it < 5; ++it) {
        int jb = it * 64;
        if (jb < M) {
            int cnt = min(64, M - jb);
            for (int jj = 0; jj < cnt; ++jj) {
                float pj = __shfl(p[it], jj);
                u += pj * ts[(jb + jj) * TSP + lane];
            }
        }
    }
    u *= inv;
    kqs[w * 64 + lane] = u;                         // reuse slot (intra-wave)
    float o = bbv[lane];
    const float2* u2 = (const float2*)(kqs + w * 64);
    #pragma unroll 8
    for (int k = 0; k < 32; ++k) {
        float2 uu = u2[k];
        o += Bt[(2 * k) * 64 + lane] * uu.x + Bt[(2 * k + 1) * 64 + lane] * uu.y;
    }
    if (ydst) ydst[qi * 64 + lane] = o;
    if (!wflag || wflag[qi]) tcn[(size_t)lane * NTOK + tok[qi]] = o;   // final value
}

// ---------------------------------------------------------------------------
// Trilinear x4 upsample, two-stage: z-lerp plane -> x-lerped rows (pzx) ->
// y-lerp via aligned b128 LDS reads; nontemporal float4 stores (512 MB stream).
// Lerp expression trees identical to the verified previous version.
// ---------------------------------------------------------------------------
__global__ __launch_bounds__(256) void upsample_kernel(const float* __restrict__ h,
                                                       float* __restrict__ out) {
    int bc = blockIdx.x;
    int c = bc >> 7, zo = bc & 127;
    __shared__ float pz[1024];        // 32x32 z-lerped plane
    __shared__ float pzx[32 * 128];   // x-lerped rows, 16 KB
    __shared__ float wtab[128];
    __shared__ int   itab[128];
    int tid = threadIdx.x;
    const float scale = (float)(31.0 / 127.0);
    if (tid < 128) {
        float p = (float)tid * scale;
        int i0 = (int)floorf(p);
        if (i0 > 31) i0 = 31;
        itab[tid] = i0;
        wtab[tid] = p - (float)i0;
    }
    float pzf = (float)zo * scale;
    int zi0 = (int)floorf(pzf);
    if (zi0 > 31) zi0 = 31;
    int zi1 = min(zi0 + 1, 31);
    float wz = pzf - (float)zi0;
    const f32x4* pl0 = (const f32x4*)(h + (size_t)(c * 32 + zi0) * 1024);
    const f32x4* pl1 = (const f32x4*)(h + (size_t)(c * 32 + zi1) * 1024);
    f32x4 a = pl0[tid];
    f32x4 b = pl1[tid];
    ((f32x4*)pz)[tid] = a * (1.f - wz) + b * wz;
    __syncthreads();
    for (int q = tid; q < 4096; q += 256) {        // x-lerp once per (yi,xo)
        int yi = q >> 7, xo = q & 127;
        int xi0 = itab[xo];
        int xi1 = min(xi0 + 1, 31);
        float wx = wtab[xo];
        const float* r = pz + yi * 32;
        pzx[yi * 128 + xo] = r[xi0] * (1.f - wx) + r[xi1] * wx;
    }
    __syncthreads();
    f32x4* o = (f32x4*)(out + (size_t)(c * 128 + zo) * 16384);
    for (int q = 0; q < 16; ++q) {
        int Q = q * 256 + tid;
        int yo = Q >> 5, xq = Q & 31;
        int yi0 = itab[yo];
        float wy = wtab[yo];
        int yi1 = min(yi0 + 1, 31);
        f32x4 v0 = *(const f32x4*)(pzx + yi0 * 128 + xq * 4);  // 16B-aligned b128
        f32x4 v1 = *(const f32x4*)(pzx + yi1 * 128 + xq * 4);
        f32x4 v = v0 * (1.f - wy) + v1 * wy;
        __builtin_nontemporal_store(v, o + Q);
    }
}

// ---------------------------------------------------------------------------
extern "C" void kernel_launch(void* const* d_in, const int* in_sizes, int n_in,
                              void* d_out, int out_size, void* d_ws, size_t ws_size,
                              hipStream_t stream) {
    const float* x       = (const float*)d_in[0];
    const float* w_patch = (const float*)d_in[1];
    const float* b_patch = (const float*)d_in[2];
    const float* pos     = (const float*)d_in[3];
    float* out = (float*)d_out;

    // ws: tcn [0,8MB) ; tnc [8,16MB) ; youtbuf @16MB ; blob @17MB ; consts @18MB
    char* ws = (char*)d_ws;
    if (ws_size < (size_t)(20u << 20)) return;
    float* tcn    = (float*)ws;
    float* tnc    = (float*)(ws + (8u << 20));
    float* yb     = (float*)(ws + (16u << 20));
    int*   blob   = (int*)  (ws + (17u << 20));
    float* consts = (float*)(ws + (18u << 20));

    // Host-side selection + value routing. Every dilation set is a subset of
    // the dil=2 set (s%4==0 and s%6==0 both imply s even), so rounds 1/2 read
    // exclusively from previous rounds' outputs (yout rows), and each round
    // writes a token's FINAL value to tcn iff no later round touches it.
    static int h_blob[BLOB_INTS];
    static int pos2[NTOK], pos4[NTOK];
    static unsigned char f4[NTOK], f6[NTOK];
    int c2 = 0, c4 = 0, c6 = 0;
    for (int n = 0; n < NTOK; ++n) {
        int z = n >> 10, yy = (n >> 5) & 31, xx = n & 31;
        int a = z - 16, b = yy - 16, c = xx - 16;
        int dd = a * a + b * b + c * c;
        int s = (int)(std::sqrt((double)dd) + 0.5);
        bool ps = (s * s == dd);
        bool s2 = ps && (s % 2 == 0);   // covers d==0
        bool s4 = ps && (s % 4 == 0);
        bool s6 = ps && (s % 6 == 0);
        f4[n] = s4; f6[n] = s6;
        if (s2) { pos2[n] = c2; h_blob[OFF_IDX2 + c2] = n; c2++; }
        if (s4) { pos4[n] = c4; h_blob[OFF_T4 + c4] = n; c4++; }
        if (s6) { h_blob[OFF_T6 + c6] = n; c6++; }
    }
    for (int j = 0; j < c4; ++j) {
        int n = h_blob[OFF_T4 + j];
        h_blob[OFF_G1 + j] = pos2[n];                          // round-1 reads yout0
        h_blob[OFF_W1 + j] = f6[n] ? 0 : 1;                    // final unless dil6 hits it
    }
    for (int j = 0; j < c6; ++j) {
        int n = h_blob[OFF_T6 + j];
        h_blob[OFF_G2 + j] = f4[n] ? (c2 + pos4[n]) : pos2[n]; // yout1 else yout0
    }
    for (int q = 0; q < c2; ++q) {
        int n = h_blob[OFF_IDX2 + q];
        h_blob[OFF_W0 + q] = (f4[n] || f6[n]) ? 0 : 1;
    }
    hipMemcpyAsync(blob, h_blob, sizeof(h_blob), hipMemcpyHostToDevice, stream);

    patch_prep_kernel<<<1024 + 97, 256, 0, stream>>>(
        x, w_patch, b_patch, pos, tnc, tcn,
        (const float*)d_in[4],  (const float*)d_in[5],  (const float*)d_in[6],  (const float*)d_in[7],
        (const float*)d_in[8],  (const float*)d_in[9],  (const float*)d_in[10], (const float*)d_in[11],
        (const float*)d_in[12], (const float*)d_in[13], (const float*)d_in[14], (const float*)d_in[15],
        consts);

    // Round 0 (dil=2): gather patched rows from tnc, write yout rows 0..c2,
    // plus final tcn values for tokens untouched by rounds 1/2.
    dst_kernel<<<(c2 + 3) / 4, 256, 0, stream>>>(
        tnc, blob + OFF_IDX2, consts + 0 * 8448, yb,
        blob + OFF_IDX2, blob + OFF_W0, tcn, c2);
    // Round 1 (dil=4): gather from yout0 rows, write yout rows c2..c2+c4.
    dst_kernel<<<(c4 + 3) / 4, 256, 0, stream>>>(
        yb, blob + OFF_G1, consts + 1 * 8448, yb + (size_t)c2 * 64,
        blob + OFF_T4, blob + OFF_W1, tcn, c4);
    // Round 2 (dil=6): gather mixed yout0/yout1 rows; always final.
    dst_kernel<<<(c6 + 3) / 4, 256, 0, stream>>>(
        yb, blob + OFF_G2, consts + 2 * 8448, nullptr,
        blob + OFF_T6, nullptr, tcn, c6);

    upsample_kernel<<<CF * 128, 256, 0, stream>>>(tcn, out);
}